// Round 7
// baseline (131.912 us; speedup 1.0000x reference)
//
#include <hip/hip_runtime.h>
#include <hip/hip_bf16.h>
#include <stdint.h>

#define HID 1024
#define NH 16
#define HD 64
#define SEQ 2048
#define BATCH 2
#define M_TOT 4096
#define QSCALE 0.18033688011112042f  /* 0.125 * log2(e) */

typedef __attribute__((ext_vector_type(8))) short short8;
typedef __attribute__((ext_vector_type(4))) float f32x4;
typedef __attribute__((ext_vector_type(16))) float f32x16;
typedef __hip_bfloat16 bf16;

__device__ __forceinline__ void load_lds16(const void* g, void* l) {
  __builtin_amdgcn_global_load_lds(
      (const __attribute__((address_space(1))) unsigned int*)g,
      (__attribute__((address_space(3))) unsigned int*)l, 16, 0, 0);
}

__device__ __forceinline__ unsigned short f2bf_bits(float f) {
  __hip_bfloat16 h = __float2bfloat16(f);
  return *reinterpret_cast<unsigned short*>(&h);
}
__device__ __forceinline__ unsigned pack2bf(float a, float b) {
  return (unsigned)f2bf_bits(a) | ((unsigned)f2bf_bits(b) << 16);
}
__device__ __forceinline__ unsigned cvt_pk_bf16(float a, float b) {
  unsigned r;
  asm("v_cvt_pk_bf16_f32 %0, %1, %2" : "=v"(r) : "v"(a), "v"(b));
  return r;
}
__device__ __forceinline__ float bfbits2f(unsigned short u) {
  unsigned v = (unsigned)u << 16;
  float f;
  __builtin_memcpy(&f, &v, 4);
  return f;
}

// ---- split-K schedule: 24 slots per bh, hand-balanced (per-CU sums 15-19) ----
// slot = k*8 + p, where block idx -> c = idx&255, k = idx>>8, bh = c&31, p = c>>5.
__device__ const unsigned char AQT[24] = {15,15,14, 7,12,13,13,14,
                                           9, 9, 8, 4,11,11,12, 6,
                                           3, 8, 2, 1,10, 5,10, 0};
__device__ const unsigned char ALO[24] = { 0, 8, 0, 0, 0, 0, 7, 8,
                                           0, 5, 0, 0, 0, 6, 7, 0,
                                           0, 5, 0, 0, 6, 0, 0, 0};
__device__ const unsigned char AHI[24] = { 8,16, 8, 8, 7, 7,14,15,
                                           5,10, 5, 5, 6,12,13, 7,
                                           4, 9, 3, 2,11, 6, 6, 1};
// merge: qt -> slots (second valid only for qt>=8)
__device__ const unsigned char MQ0[16] = {23,19,18,16,11,21,15, 3,10, 8,22,12, 4, 5, 2, 0};
__device__ const unsigned char MQ1[16] = { 0, 0, 0, 0, 0, 0, 0, 0,17, 9,20,13,14, 6, 7, 1};

// ---------------- prep kernels ----------------
__global__ void cvt_f32_to_bf16(const float* __restrict__ in,
                                bf16* __restrict__ out, int n4) {
  int i = blockIdx.x * blockDim.x + threadIdx.x;
  if (i >= n4) return;
  float4 v = reinterpret_cast<const float4*>(in)[i];
  ushort4 o;
  o.x = f2bf_bits(v.x); o.y = f2bf_bits(v.y);
  o.z = f2bf_bits(v.z); o.w = f2bf_bits(v.w);
  reinterpret_cast<ushort4*>(out)[i] = o;
}

__global__ void transpose_cvt(const float* __restrict__ W,
                              bf16* __restrict__ WT, int K, int N) {
  __shared__ float tile[32][33];
  int n0 = blockIdx.x * 32, k0 = blockIdx.y * 32;
  int tx = threadIdx.x, ty = threadIdx.y;  // 32 x 8
#pragma unroll
  for (int i = 0; i < 32; i += 8)
    tile[ty + i][tx] = W[(size_t)(k0 + ty + i) * N + n0 + tx];
  __syncthreads();
#pragma unroll
  for (int i = 0; i < 32; i += 8)
    WT[(size_t)(n0 + ty + i) * K + k0 + tx] = __float2bfloat16(tile[tx][ty + i]);
}

// ---------------- GEMM: C[M][N] = A[M][K] * BT[N][K]^T + bias ----------------
// 2D grid, blockIdx.x = m-block fastest (XCD j owns m==j mod 8 -> small L2 set)
template <int EPI>
__global__ __launch_bounds__(256, 2)
void gemm128(const bf16* __restrict__ A, const bf16* __restrict__ BT,
             const float* __restrict__ bias,
             bf16* __restrict__ Qo, bf16* __restrict__ Ko, bf16* __restrict__ Vo,
             float* __restrict__ Fo) {
  const int Kdim = 1024;
  __shared__ bf16 As[128 * 64];
  __shared__ bf16 Bs[128 * 64];
  const int tid = threadIdx.x;
  const int wid = tid >> 6, lane = tid & 63;
  const int m0 = blockIdx.x * 128;
  const int n0 = blockIdx.y * 128;
  const int wrow = (wid >> 1) * 64, wcol = (wid & 1) * 64;

  f32x4 acc[4][4];
#pragma unroll
  for (int rb = 0; rb < 4; ++rb)
#pragma unroll
    for (int cb = 0; cb < 4; ++cb)
      acc[rb][cb] = (f32x4){0.f, 0.f, 0.f, 0.f};

  const int lr = lane >> 3;
  const int lc = (lane & 7) * 8;
  const int fr = lane & 15, fk = (lane >> 4) * 8;

  for (int kt = 0; kt < Kdim / 64; ++kt) {
    __syncthreads();
#pragma unroll
    for (int t = 0; t < 4; ++t) {
      int i = wid * 4 + t;
      int row = i * 8 + lr;
      load_lds16(A + (size_t)(m0 + row) * Kdim + kt * 64 + lc, (char*)As + i * 1024);
      load_lds16(BT + (size_t)(n0 + row) * Kdim + kt * 64 + lc, (char*)Bs + i * 1024);
    }
    __syncthreads();

    short8 af[4][2], bf_[4][2];
#pragma unroll
    for (int rb = 0; rb < 4; ++rb)
#pragma unroll
      for (int kk = 0; kk < 2; ++kk) {
        af[rb][kk] = *(const short8*)&As[(wrow + rb * 16 + fr) * 64 + kk * 32 + fk];
        bf_[rb][kk] = *(const short8*)&Bs[(wcol + rb * 16 + fr) * 64 + kk * 32 + fk];
      }
#pragma unroll
    for (int rb = 0; rb < 4; ++rb)
#pragma unroll
      for (int cb = 0; cb < 4; ++cb)
#pragma unroll
        for (int kk = 0; kk < 2; ++kk)
          acc[rb][cb] = __builtin_amdgcn_mfma_f32_16x16x32_bf16(
              af[rb][kk], bf_[cb][kk], acc[rb][cb], 0, 0, 0);
  }

  const int fg = (lane >> 4) * 4;
  float bv[4];
#pragma unroll
  for (int cb = 0; cb < 4; ++cb) bv[cb] = bias[n0 + wcol + cb * 16 + fr];

  if (EPI == 0) {
#pragma unroll
    for (int rb = 0; rb < 4; ++rb) {
      int r0 = m0 + wrow + rb * 16 + fg;
#pragma unroll
      for (int cb = 0; cb < 4; ++cb) {
        int n = n0 + wcol + cb * 16 + fr;
        int part = n >> 10;
        int d = n & 1023;
        int h = d >> 6, hd = d & 63;
#pragma unroll
        for (int j = 0; j < 4; ++j) {
          int m = r0 + j;
          int b = m >> 11, s = m & 2047;
          size_t bh = (size_t)(b * NH + h);
          float vv = acc[rb][cb][j] + bv[cb];
          if (part == 0) {
            Qo[(bh * SEQ + s) * HD + hd] = __float2bfloat16(vv * QSCALE);
          } else if (part == 1) {
            Ko[(bh * SEQ + s) * HD + hd] = __float2bfloat16(vv);
          } else {
            Vo[(bh * HD + hd) * SEQ + s] = __float2bfloat16(vv);
          }
        }
      }
    }
  } else {
#pragma unroll
    for (int rb = 0; rb < 4; ++rb) {
      int r0 = m0 + wrow + rb * 16 + fg;
#pragma unroll
      for (int cb = 0; cb < 4; ++cb) {
        int n = n0 + wcol + cb * 16 + fr;
#pragma unroll
        for (int j = 0; j < 4; ++j)
          Fo[(size_t)(r0 + j) * HID + n] = acc[rb][cb][j] + bv[cb];
      }
    }
  }
}

// ---------------- causal flash attention, split-K partials ----------------
// Block = (bh, slot): one q-tile qt, kv pair range [lo,hi). 768 blocks, all
// co-resident (3/CU, 12 waves/CU). Fixed-zero-max softmax -> partials merge
// by addition. Writes unnormalized O (bf16) + row-sum l (f32).
__global__ __launch_bounds__(256, 2)
void attn_kernel(const bf16* __restrict__ Q, const bf16* __restrict__ K,
                 const bf16* __restrict__ VT, bf16* __restrict__ Opart,
                 float* __restrict__ lsum) {
  __shared__ char smem[32768];   // buf b at b*16384: K 8KB | V 8KB
  const int tid = threadIdx.x, wid = tid >> 6, lane = tid & 63;
  const int idx = blockIdx.x;
  const int c = idx & 255, k = idx >> 8;
  const int bh = c & 31, p = c >> 5;
  const int sl = k * 8 + p;
  const int qt = AQT[sl];
  const int t0 = ALO[sl] * 2, t1 = AHI[sl] * 2;   // tile range (64-kv units)
  const int b = bh >> 4, h = bh & 15;
  const size_t base = (size_t)bh * SEQ * HD;
  const int q0 = qt * 128 + wid * 32;

  const int fr = lane & 31, hi = lane >> 5;
  const int lr = lane >> 3;              // 0..7
  const int cc = lane & 7;
  const int qg = q0 + fr;
  const int gc = (cc ^ lr) * 8;          // pre-swizzled source chunk

  // Q fragments (B operand), hoisted. Q pre-scaled by QSCALE (incl. log2e).
  short8 qf[4];
  const bf16* qp = Q + base + (size_t)qg * HD;
#pragma unroll
  for (int kc = 0; kc < 4; ++kc)
    qf[kc] = *(const short8*)(qp + kc * 16 + hi * 8);

  f32x16 oa[2], ob[2];
#pragma unroll
  for (int da = 0; da < 2; ++da)
#pragma unroll
    for (int r = 0; r < 16; ++r) { oa[da][r] = 0.f; ob[da][r] = 0.f; }
  float lpart = 0.f;

  // one 64-kv tile: QK -> mask -> exp2 -> pack -> PV into oc[2]
  auto tile_compute = [&](const char* sb_t, int kv0, f32x16 (&oc)[2]) {
    f32x16 sa[2];
    __builtin_amdgcn_s_setprio(1);
#pragma unroll
    for (int kb = 0; kb < 2; ++kb) {
#pragma unroll
      for (int r = 0; r < 16; ++r) sa[kb][r] = 0.f;
      const int row = kb * 32 + fr;
      const int swz = (row & 7) << 4;
#pragma unroll
      for (int kc = 0; kc < 4; ++kc) {
        short8 kf = *(const short8*)(sb_t + row * 128 + ((kc * 32 + hi * 16) ^ swz));
        sa[kb] = __builtin_amdgcn_mfma_f32_32x32x16_bf16(kf, qf[kc], sa[kb], 0, 0, 0);
      }
    }
    __builtin_amdgcn_s_setprio(0);

    if (kv0 + 63 > q0) {                 // causal mask, boundary tiles only
#pragma unroll
      for (int kb = 0; kb < 2; ++kb)
#pragma unroll
        for (int r = 0; r < 16; ++r) {
          int kvg = kv0 + kb * 32 + (r & 3) + 8 * (r >> 2) + 4 * hi;
          sa[kb][r] = (kvg > qg) ? -1e30f : sa[kb][r];
        }
    }

    float s0 = 0.f, s1 = 0.f, s2 = 0.f, s3 = 0.f;
#pragma unroll
    for (int kb = 0; kb < 2; ++kb)
#pragma unroll
      for (int r = 0; r < 16; ++r) {
        float e = __builtin_exp2f(sa[kb][r]);
        sa[kb][r] = e;
        if ((r & 3) == 0)      s0 += e;
        else if ((r & 3) == 1) s1 += e;
        else if ((r & 3) == 2) s2 += e;
        else                   s3 += e;
      }
    lpart += (s0 + s1) + (s2 + s3);

    // pk[kb][i] holds kv = kb*32 + 8*(i>>1) + 2*(i&1) + 4*hi + {0,1};
    // PV word w of slice ks needs kv = ks*16 + hi*8 + 2w + {0,1}.
    unsigned pk[2][8], px[2][8];
#pragma unroll
    for (int kb = 0; kb < 2; ++kb) {
#pragma unroll
      for (int i = 0; i < 8; ++i)
        pk[kb][i] = cvt_pk_bf16(sa[kb][2 * i], sa[kb][2 * i + 1]);
#pragma unroll
      for (int i = 0; i < 8; ++i)
        px[kb][i] = (unsigned)__shfl_xor((int)pk[kb][i], 32);
    }

    __builtin_amdgcn_s_setprio(1);
#pragma unroll
    for (int da = 0; da < 2; ++da) {
      const int row = da * 32 + fr;
      const int swz = (row & 7) << 4;
#pragma unroll
      for (int ks = 0; ks < 4; ++ks) {
        short8 vf = *(const short8*)(sb_t + 8192 + row * 128 +
                                     ((ks * 32 + hi * 16) ^ swz));
        const int kb = ks >> 1, g = (ks & 1) * 4;
        union { unsigned u[4]; short8 s; } pf;
        pf.u[0] = hi ? px[kb][g + 2] : pk[kb][g + 0];
        pf.u[1] = hi ? px[kb][g + 3] : pk[kb][g + 1];
        pf.u[2] = hi ? pk[kb][g + 2] : px[kb][g + 0];
        pf.u[3] = hi ? pk[kb][g + 3] : px[kb][g + 1];
        oc[da] = __builtin_amdgcn_mfma_f32_32x32x16_bf16(vf, pf.s, oc[da], 0, 0, 0);
      }
    }
    __builtin_amdgcn_s_setprio(0);
  };

  // prologue: stage tile t0 into buf 0
#pragma unroll
  for (int t = 0; t < 2; ++t) {
    int i = wid * 2 + t;
    load_lds16(K + base + (size_t)(t0 * 64 + i * 8 + lr) * HD + gc, smem + i * 1024);
    load_lds16(VT + base + (size_t)(i * 8 + lr) * SEQ + t0 * 64 + gc,
               smem + 8192 + i * 1024);
  }
  __syncthreads();

  for (int t = t0; t < t1; ++t) {
    char* sb = smem + (t & 1) * 16384;
    if (t + 1 < t1) {                    // stage next tile into other buffer
      char* nb = smem + ((t + 1) & 1) * 16384;
      const int nv = (t + 1) * 64;
#pragma unroll
      for (int u = 0; u < 2; ++u) {
        int i = wid * 2 + u;
        load_lds16(K + base + (size_t)(nv + i * 8 + lr) * HD + gc, nb + i * 1024);
        load_lds16(VT + base + (size_t)(i * 8 + lr) * SEQ + nv + gc,
                   nb + 8192 + i * 1024);
      }
    }
    const int kv0 = t * 64;
    if (kv0 <= q0 + 31) {
      if (t & 1) tile_compute(sb, kv0, ob);
      else       tile_compute(sb, kv0, oa);
    }
    __syncthreads();   // drains prefetch; safe buffer swap
  }

  // ---------------- epilogue: write unnormalized partials ----------------
  const float lrun = lpart + __shfl_xor(lpart, 32);
  const size_t rowbase = (size_t)(bh * 24 + sl) * 128 + wid * 32;
  if (hi == 0) lsum[rowbase + fr] = lrun;

  char* ep = smem + wid * 4096;          // [32 q][64 d] bf16, swizzled
#pragma unroll
  for (int da = 0; da < 2; ++da)
#pragma unroll
    for (int rg = 0; rg < 4; ++rg) {
      int d0 = da * 64 + rg * 16 + hi * 8;  // byte offset of d within row
      float v0 = oa[da][rg * 4 + 0] + ob[da][rg * 4 + 0];
      float v1 = oa[da][rg * 4 + 1] + ob[da][rg * 4 + 1];
      float v2 = oa[da][rg * 4 + 2] + ob[da][rg * 4 + 2];
      float v3 = oa[da][rg * 4 + 3] + ob[da][rg * 4 + 3];
      uint2 wv; wv.x = pack2bf(v0, v1); wv.y = pack2bf(v2, v3);
      *(uint2*)(ep + fr * 128 + (d0 ^ ((fr & 7) << 4))) = wv;
    }
  // per-wave data only -> same-wave lgkmcnt ordering suffices
#pragma unroll
  for (int pq = 0; pq < 4; ++pq) {
    int qr = pq * 8 + lr;
    uint4 v = *(const uint4*)(ep + qr * 128 + ((cc * 16) ^ ((qr & 7) << 4)));
    *(uint4*)(Opart + (rowbase + qr) * 64 + cc * 8) = v;
  }
}

// ---------------- merge: out = (sum O_i) / (sum l_i) ----------------
__global__ __launch_bounds__(256)
void attn_merge(const bf16* __restrict__ Opart, const float* __restrict__ lsum,
                bf16* __restrict__ ctxb) {
  int gid = blockIdx.x * 256 + threadIdx.x;   // 524288 total
  int oct = gid & 7;
  int s = (gid >> 3) & 2047;
  int bh = gid >> 14;
  int qt = s >> 7, ql = s & 127;
  size_t r0 = (size_t)(bh * 24 + MQ0[qt]) * 128 + ql;
  float l = lsum[r0];
  union { uint4 u; unsigned short us[8]; } a;
  a.u = *(const uint4*)(Opart + r0 * 64 + oct * 8);
  float acc[8];
#pragma unroll
  for (int i = 0; i < 8; ++i) acc[i] = bfbits2f(a.us[i]);
  if (qt >= 8) {
    size_t r1 = (size_t)(bh * 24 + MQ1[qt]) * 128 + ql;
    l += lsum[r1];
    union { uint4 u; unsigned short us[8]; } bq;
    bq.u = *(const uint4*)(Opart + r1 * 64 + oct * 8);
#pragma unroll
    for (int i = 0; i < 8; ++i) acc[i] += bfbits2f(bq.us[i]);
  }
  float inv = 1.f / l;
  uint4 o;
  o.x = pack2bf(acc[0] * inv, acc[1] * inv);
  o.y = pack2bf(acc[2] * inv, acc[3] * inv);
  o.z = pack2bf(acc[4] * inv, acc[5] * inv);
  o.w = pack2bf(acc[6] * inv, acc[7] * inv);
  int b = bh >> 4, h = bh & 15;
  *(uint4*)(ctxb + (size_t)(b * SEQ + s) * HID + h * 64 + oct * 8) = o;
}

// ---------------- launch ----------------
extern "C" void kernel_launch(void* const* d_in, const int* in_sizes, int n_in,
                              void* d_out, int out_size, void* d_ws, size_t ws_size,
                              hipStream_t stream) {
  const float* x      = (const float*)d_in[0];
  const float* W_attn = (const float*)d_in[1];
  const float* b_attn = (const float*)d_in[2];
  const float* W_proj = (const float*)d_in[3];
  const float* b_proj = (const float*)d_in[4];
  float* out = (float*)d_out;

  char* ws = (char*)d_ws;
  const size_t MB = 1u << 20;
  bf16*  WTp   = (bf16*)(ws + 0);        //  0..2   (live: all)
  bf16*  ctxb  = (bf16*)(ws + 2 * MB);   //  2..10  (merge->gemm1)
  bf16*  Qw    = (bf16*)(ws + 10 * MB);  // 10..18
  bf16*  Kw    = (bf16*)(ws + 18 * MB);  // 18..26
  bf16*  VTw   = (bf16*)(ws + 26 * MB);  // 26..34
  bf16*  xb    = (bf16*)(ws + 34 * MB);  // 34..42 (prep+gemm0 only)
  bf16*  WTa   = (bf16*)(ws + 42 * MB);  // 42..48 (prep+gemm0 only)
  bf16*  Opart = (bf16*)(ws + 34 * MB);  // 34..46 (attn+merge; reuses xb/WTa)
  float* lsumw = (float*)(ws + 46 * MB); // 46..46.4

  cvt_f32_to_bf16<<<(M_TOT * HID / 4 + 255) / 256, 256, 0, stream>>>(x, xb, M_TOT * HID / 4);
  transpose_cvt<<<dim3(3 * HID / 32, HID / 32), dim3(32, 8), 0, stream>>>(W_attn, WTa, HID, 3 * HID);
  transpose_cvt<<<dim3(HID / 32, HID / 32), dim3(32, 8), 0, stream>>>(W_proj, WTp, HID, HID);

  gemm128<0><<<dim3(M_TOT / 128, 3 * HID / 128), 256, 0, stream>>>(
      xb, WTa, b_attn, Qw, Kw, VTw, nullptr);

  attn_kernel<<<dim3(768), 256, 0, stream>>>(Qw, Kw, VTw, Opart, lsumw);
  attn_merge<<<dim3(2048), 256, 0, stream>>>(Opart, lsumw, ctxb);

  gemm128<1><<<dim3(M_TOT / 128, HID / 128), 256, 0, stream>>>(
      ctxb, WTp, b_proj, nullptr, nullptr, nullptr, out);
}

// Round 8
// 113.784 us; speedup vs baseline: 1.1593x; 1.1593x over previous
//
#include <hip/hip_runtime.h>
#include <hip/hip_bf16.h>
#include <stdint.h>

#define HID 1024
#define NH 16
#define HD 64
#define SEQ 2048
#define BATCH 2
#define M_TOT 4096
#define QSCALE 0.18033688011112042f  /* 0.125 * log2(e) */

typedef __attribute__((ext_vector_type(8))) short short8;
typedef __attribute__((ext_vector_type(4))) float f32x4;
typedef __attribute__((ext_vector_type(16))) float f32x16;
typedef __hip_bfloat16 bf16;

__device__ __forceinline__ void load_lds16(const void* g, void* l) {
  __builtin_amdgcn_global_load_lds(
      (const __attribute__((address_space(1))) unsigned int*)g,
      (__attribute__((address_space(3))) unsigned int*)l, 16, 0, 0);
}

__device__ __forceinline__ unsigned short f2bf_bits(float f) {
  __hip_bfloat16 h = __float2bfloat16(f);
  return *reinterpret_cast<unsigned short*>(&h);
}
__device__ __forceinline__ unsigned pack2bf(float a, float b) {
  return (unsigned)f2bf_bits(a) | ((unsigned)f2bf_bits(b) << 16);
}
__device__ __forceinline__ unsigned cvt_pk_bf16(float a, float b) {
  unsigned r;
  asm("v_cvt_pk_bf16_f32 %0, %1, %2" : "=v"(r) : "v"(a), "v"(b));
  return r;
}

// ---------------- prep kernels ----------------
__global__ void cvt_f32_to_bf16(const float* __restrict__ in,
                                bf16* __restrict__ out, int n4) {
  int i = blockIdx.x * blockDim.x + threadIdx.x;
  if (i >= n4) return;
  float4 v = reinterpret_cast<const float4*>(in)[i];
  ushort4 o;
  o.x = f2bf_bits(v.x); o.y = f2bf_bits(v.y);
  o.z = f2bf_bits(v.z); o.w = f2bf_bits(v.w);
  reinterpret_cast<ushort4*>(out)[i] = o;
}

// both W transposes in one launch: x-blocks [0,96) -> W_attn, [96,128) -> W_proj
__global__ void transpose_cvt2(const float* __restrict__ Wa, bf16* __restrict__ WTa,
                               const float* __restrict__ Wp, bf16* __restrict__ WTp) {
  __shared__ float tile[32][33];
  int bx = blockIdx.x;
  const float* W; bf16* WT; int N;
  if (bx < 96) { W = Wa; WT = WTa; N = 3072; }
  else         { W = Wp; WT = WTp; N = 1024; bx -= 96; }
  const int K = 1024;
  int n0 = bx * 32, k0 = blockIdx.y * 32;
  int tx = threadIdx.x, ty = threadIdx.y;  // 32 x 8
#pragma unroll
  for (int i = 0; i < 32; i += 8)
    tile[ty + i][tx] = W[(size_t)(k0 + ty + i) * N + n0 + tx];
  __syncthreads();
#pragma unroll
  for (int i = 0; i < 32; i += 8)
    WT[(size_t)(n0 + ty + i) * K + k0 + tx] = __float2bfloat16(tile[tx][ty + i]);
}

// ---------------- GEMM: C[M][N] = A[M][K] * BT[N][K]^T + bias ----------------
// 2D grid, blockIdx.x = m-block fastest (XCD j owns m==j mod 8 -> small L2 set)
template <int EPI>
__global__ __launch_bounds__(256, 2)
void gemm128(const bf16* __restrict__ A, const bf16* __restrict__ BT,
             const float* __restrict__ bias,
             bf16* __restrict__ Qo, bf16* __restrict__ Ko, bf16* __restrict__ Vo,
             float* __restrict__ Fo) {
  const int Kdim = 1024;
  __shared__ bf16 As[128 * 64];
  __shared__ bf16 Bs[128 * 64];
  const int tid = threadIdx.x;
  const int wid = tid >> 6, lane = tid & 63;
  const int m0 = blockIdx.x * 128;
  const int n0 = blockIdx.y * 128;
  const int wrow = (wid >> 1) * 64, wcol = (wid & 1) * 64;

  f32x4 acc[4][4];
#pragma unroll
  for (int rb = 0; rb < 4; ++rb)
#pragma unroll
    for (int cb = 0; cb < 4; ++cb)
      acc[rb][cb] = (f32x4){0.f, 0.f, 0.f, 0.f};

  const int lr = lane >> 3;
  const int cc = lane & 7;
  const int lc = cc * 8;
  const int fr = lane & 15, fk = (lane >> 4) * 8;

  for (int kt = 0; kt < Kdim / 64; ++kt) {
    __syncthreads();
#pragma unroll
    for (int t = 0; t < 4; ++t) {
      int i = wid * 4 + t;
      int row = i * 8 + lr;
      load_lds16(A + (size_t)(m0 + row) * Kdim + kt * 64 + lc, (char*)As + i * 1024);
      load_lds16(BT + (size_t)(n0 + row) * Kdim + kt * 64 + lc, (char*)Bs + i * 1024);
    }
    __syncthreads();

    short8 af[4][2], bf_[4][2];
#pragma unroll
    for (int rb = 0; rb < 4; ++rb)
#pragma unroll
      for (int kk = 0; kk < 2; ++kk) {
        af[rb][kk] = *(const short8*)&As[(wrow + rb * 16 + fr) * 64 + kk * 32 + fk];
        bf_[rb][kk] = *(const short8*)&Bs[(wcol + rb * 16 + fr) * 64 + kk * 32 + fk];
      }
#pragma unroll
    for (int rb = 0; rb < 4; ++rb)
#pragma unroll
      for (int cb = 0; cb < 4; ++cb)
#pragma unroll
        for (int kk = 0; kk < 2; ++kk)
          acc[rb][cb] = __builtin_amdgcn_mfma_f32_16x16x32_bf16(
              af[rb][kk], bf_[cb][kk], acc[rb][cb], 0, 0, 0);
  }

  const int fg = (lane >> 4) * 4;
  float bv[4];
#pragma unroll
  for (int cb = 0; cb < 4; ++cb) bv[cb] = bias[n0 + wcol + cb * 16 + fr];

  if (EPI == 0) {
    // coalesced QKV scatter via per-wave LDS transpose.
    // wave tile = 64 s-rows x 64 cols = exactly one head's 64 hd.
    __syncthreads();                       // done with As/Bs K-loop use
    char* ep = (wid < 2 ? (char*)As : (char*)Bs) + (wid & 1) * 8192;
    const int ncol = n0 + wcol;
    const int part = ncol >> 10;           // 0=Q 1=K 2=V (uniform per wave)
    const int h = (ncol & 1023) >> 6;      // head (uniform)
    const int b = m0 >> 11;
    const int s_base = (m0 + wrow) & 2047;
    const size_t hb = (size_t)(b * NH + h);

    if (part < 2) {
      const float qs = (part == 0) ? QSCALE : 1.f;
      // [s 64][128B] swizzled: 64 scalar b16 writes
#pragma unroll
      for (int rb = 0; rb < 4; ++rb)
#pragma unroll
        for (int cb = 0; cb < 4; ++cb)
#pragma unroll
          for (int j = 0; j < 4; ++j) {
            int row = rb * 16 + fg + j;
            int colb = (cb * 16 + fr) * 2;
            *(unsigned short*)(ep + row * 128 + (colb ^ ((row & 7) << 4))) =
                f2bf_bits((acc[rb][cb][j] + bv[cb]) * qs);
          }
      bf16* dst = (part == 0 ? Qo : Ko) + hb * SEQ * HD;
#pragma unroll
      for (int p = 0; p < 8; ++p) {        // 8 x (8 rows x 128B) stores
        int row = p * 8 + lr;
        uint4 v = *(const uint4*)(ep + row * 128 + ((cc * 16) ^ ((row & 7) << 4)));
        *(uint4*)(dst + (size_t)(s_base + row) * HD + cc * 8) = v;
      }
    } else {
      // V: [hd 64][s 64 x 2B =128B] swizzled; j-values are consecutive s -> b64 packs
#pragma unroll
      for (int rb = 0; rb < 4; ++rb)
#pragma unroll
        for (int cb = 0; cb < 4; ++cb) {
          int cV = cb * 16 + fr;           // hd
          int r0 = (rb * 16 + fg) * 2;     // byte offset of s
          uint2 wv;
          wv.x = pack2bf(acc[rb][cb][0] + bv[cb], acc[rb][cb][1] + bv[cb]);
          wv.y = pack2bf(acc[rb][cb][2] + bv[cb], acc[rb][cb][3] + bv[cb]);
          *(uint2*)(ep + cV * 128 + (r0 ^ ((cV & 7) << 4))) = wv;
        }
      bf16* dstV = Vo + hb * HD * SEQ;
#pragma unroll
      for (int p = 0; p < 8; ++p) {
        int hd = p * 8 + lr;
        uint4 v = *(const uint4*)(ep + hd * 128 + ((cc * 16) ^ ((hd & 7) << 4)));
        *(uint4*)(dstV + (size_t)hd * SEQ + s_base + cc * 8) = v;
      }
    }
  } else {
#pragma unroll
    for (int rb = 0; rb < 4; ++rb) {
      int r0 = m0 + wrow + rb * 16 + fg;
#pragma unroll
      for (int cb = 0; cb < 4; ++cb) {
        int n = n0 + wcol + cb * 16 + fr;
#pragma unroll
        for (int j = 0; j < 4; ++j)
          Fo[(size_t)(r0 + j) * HID + n] = acc[rb][cb][j] + bv[cb];
      }
    }
  }
}

// ---------------- causal flash attention, swapped-operand 32x32 ----------------
// (R6 structure, unchanged: fixed-zero-max softmax, pair-unrolled, dbuf 2x32KB)
__global__ __launch_bounds__(256, 2)
void attn_kernel(const bf16* __restrict__ Q, const bf16* __restrict__ K,
                 const bf16* __restrict__ VT, bf16* __restrict__ ctx) {
  __shared__ char smem[65536];  // buf b at b*32768: {K0,V0,K1,V1} x 8KB
  const int tid = threadIdx.x, wid = tid >> 6, lane = tid & 63;
  const int idx = blockIdx.x;
  const int qt = (idx < 256) ? (15 - (idx >> 5)) : ((idx - 256) >> 5);
  const int bh = idx & 31;
  const int b = bh >> 4, h = bh & 15;
  const size_t base = (size_t)bh * SEQ * HD;
  const int q0 = qt * 128 + wid * 32;

  const int fr = lane & 31, hi = lane >> 5;
  const int lr = lane >> 3;              // 0..7
  const int cc = lane & 7;
  const int qg = q0 + fr;
  const int gc = (cc ^ lr) * 8;          // pre-swizzled source chunk

  short8 qf[4];
  const bf16* qp = Q + base + (size_t)qg * HD;
#pragma unroll
  for (int kc = 0; kc < 4; ++kc)
    qf[kc] = *(const short8*)(qp + kc * 16 + hi * 8);

  f32x16 oa[2], ob[2];
#pragma unroll
  for (int da = 0; da < 2; ++da)
#pragma unroll
    for (int r = 0; r < 16; ++r) { oa[da][r] = 0.f; ob[da][r] = 0.f; }
  float lpart = 0.f;

  auto tile_compute = [&](const char* sb_t, int kv0, f32x16 (&oc)[2]) {
    f32x16 sa[2];
    __builtin_amdgcn_s_setprio(1);
#pragma unroll
    for (int kb = 0; kb < 2; ++kb) {
#pragma unroll
      for (int r = 0; r < 16; ++r) sa[kb][r] = 0.f;
      const int row = kb * 32 + fr;
      const int swz = (row & 7) << 4;
#pragma unroll
      for (int kc = 0; kc < 4; ++kc) {
        short8 kf = *(const short8*)(sb_t + row * 128 + ((kc * 32 + hi * 16) ^ swz));
        sa[kb] = __builtin_amdgcn_mfma_f32_32x32x16_bf16(kf, qf[kc], sa[kb], 0, 0, 0);
      }
    }
    __builtin_amdgcn_s_setprio(0);

    if (kv0 + 63 > q0) {
#pragma unroll
      for (int kb = 0; kb < 2; ++kb)
#pragma unroll
        for (int r = 0; r < 16; ++r) {
          int kvg = kv0 + kb * 32 + (r & 3) + 8 * (r >> 2) + 4 * hi;
          sa[kb][r] = (kvg > qg) ? -1e30f : sa[kb][r];
        }
    }

    float s0 = 0.f, s1 = 0.f, s2 = 0.f, s3 = 0.f;
#pragma unroll
    for (int kb = 0; kb < 2; ++kb)
#pragma unroll
      for (int r = 0; r < 16; ++r) {
        float e = __builtin_exp2f(sa[kb][r]);
        sa[kb][r] = e;
        if ((r & 3) == 0)      s0 += e;
        else if ((r & 3) == 1) s1 += e;
        else if ((r & 3) == 2) s2 += e;
        else                   s3 += e;
      }
    lpart += (s0 + s1) + (s2 + s3);

    unsigned pk[2][8], px[2][8];
#pragma unroll
    for (int kb = 0; kb < 2; ++kb) {
#pragma unroll
      for (int i = 0; i < 8; ++i)
        pk[kb][i] = cvt_pk_bf16(sa[kb][2 * i], sa[kb][2 * i + 1]);
#pragma unroll
      for (int i = 0; i < 8; ++i)
        px[kb][i] = (unsigned)__shfl_xor((int)pk[kb][i], 32);
    }

    __builtin_amdgcn_s_setprio(1);
#pragma unroll
    for (int da = 0; da < 2; ++da) {
      const int row = da * 32 + fr;
      const int swz = (row & 7) << 4;
#pragma unroll
      for (int ks = 0; ks < 4; ++ks) {
        short8 vf = *(const short8*)(sb_t + 8192 + row * 128 +
                                     ((ks * 32 + hi * 16) ^ swz));
        const int kb = ks >> 1, g = (ks & 1) * 4;
        union { unsigned u[4]; short8 s; } pf;
        pf.u[0] = hi ? px[kb][g + 2] : pk[kb][g + 0];
        pf.u[1] = hi ? px[kb][g + 3] : pk[kb][g + 1];
        pf.u[2] = hi ? pk[kb][g + 2] : px[kb][g + 0];
        pf.u[3] = hi ? pk[kb][g + 3] : px[kb][g + 1];
        oc[da] = __builtin_amdgcn_mfma_f32_32x32x16_bf16(vf, pf.s, oc[da], 0, 0, 0);
      }
    }
    __builtin_amdgcn_s_setprio(0);
  };

  const int npair = qt + 1;              // 128 kv per pair

#pragma unroll
  for (int u = 0; u < 2; ++u)
#pragma unroll
    for (int t = 0; t < 2; ++t) {
      int i = wid * 2 + t;
      load_lds16(K + base + (size_t)(u * 64 + i * 8 + lr) * HD + gc,
                 smem + u * 16384 + i * 1024);
      load_lds16(VT + base + (size_t)(i * 8 + lr) * SEQ + u * 64 + gc,
                 smem + u * 16384 + 8192 + i * 1024);
    }
  __syncthreads();

  for (int j = 0; j < npair; ++j) {
    char* sb = smem + (j & 1) * 32768;

    if (j + 1 < npair) {
      char* nb = smem + ((j + 1) & 1) * 32768;
      const int nv = (j + 1) * 128;
#pragma unroll
      for (int u = 0; u < 2; ++u)
#pragma unroll
        for (int t = 0; t < 2; ++t) {
          int i = wid * 2 + t;
          load_lds16(K + base + (size_t)(nv + u * 64 + i * 8 + lr) * HD + gc,
                     nb + u * 16384 + i * 1024);
          load_lds16(VT + base + (size_t)(i * 8 + lr) * SEQ + nv + u * 64 + gc,
                     nb + u * 16384 + 8192 + i * 1024);
        }
    }

    const int kv0 = j * 128;
    if (kv0 <= q0 + 31)      tile_compute(sb,         kv0,      oa);
    if (kv0 + 64 <= q0 + 31) tile_compute(sb + 16384, kv0 + 64, ob);

    __syncthreads();
  }

  const float lrun = lpart + __shfl_xor(lpart, 32);
  const float inv = 1.f / lrun;
  char* ep = smem + wid * 4096;
#pragma unroll
  for (int da = 0; da < 2; ++da)
#pragma unroll
    for (int rg = 0; rg < 4; ++rg) {
      int d0 = da * 64 + rg * 16 + hi * 8;
      float v0 = (oa[da][rg * 4 + 0] + ob[da][rg * 4 + 0]) * inv;
      float v1 = (oa[da][rg * 4 + 1] + ob[da][rg * 4 + 1]) * inv;
      float v2 = (oa[da][rg * 4 + 2] + ob[da][rg * 4 + 2]) * inv;
      float v3 = (oa[da][rg * 4 + 3] + ob[da][rg * 4 + 3]) * inv;
      uint2 wv; wv.x = pack2bf(v0, v1); wv.y = pack2bf(v2, v3);
      *(uint2*)(ep + fr * 128 + (d0 ^ ((fr & 7) << 4))) = wv;
    }
#pragma unroll
  for (int p = 0; p < 4; ++p) {
    int qr = p * 8 + lr;
    uint4 v = *(const uint4*)(ep + qr * 128 + ((cc * 16) ^ ((qr & 7) << 4)));
    int s = q0 + qr;
    *(uint4*)(ctx + (size_t)(b * SEQ + s) * HID + h * 64 + cc * 8) = v;
  }
}

// ---------------- launch ----------------
extern "C" void kernel_launch(void* const* d_in, const int* in_sizes, int n_in,
                              void* d_out, int out_size, void* d_ws, size_t ws_size,
                              hipStream_t stream) {
  const float* x      = (const float*)d_in[0];
  const float* W_attn = (const float*)d_in[1];
  const float* b_attn = (const float*)d_in[2];
  const float* W_proj = (const float*)d_in[3];
  const float* b_proj = (const float*)d_in[4];
  float* out = (float*)d_out;

  char* ws = (char*)d_ws;
  const size_t MB = 1u << 20;
  bf16* xb   = (bf16*)(ws + 0);
  bf16* WTa  = (bf16*)(ws + 8 * MB);
  bf16* WTp  = (bf16*)(ws + 14 * MB);
  bf16* Qw   = (bf16*)(ws + 16 * MB);
  bf16* Kw   = (bf16*)(ws + 24 * MB);
  bf16* VTw  = (bf16*)(ws + 32 * MB);
  bf16* ctxb = (bf16*)(ws + 40 * MB);

  cvt_f32_to_bf16<<<(M_TOT * HID / 4 + 255) / 256, 256, 0, stream>>>(x, xb, M_TOT * HID / 4);
  transpose_cvt2<<<dim3(128, 32), dim3(32, 8), 0, stream>>>(W_attn, WTa, W_proj, WTp);

  gemm128<0><<<dim3(M_TOT / 128, 3 * HID / 128), 256, 0, stream>>>(
      xb, WTa, b_attn, Qw, Kw, VTw, nullptr);

  attn_kernel<<<dim3(512), 256, 0, stream>>>(Qw, Kw, VTw, ctxb);

  gemm128<1><<<dim3(M_TOT / 128, HID / 128), 256, 0, stream>>>(
      ctxb, WTp, b_proj, nullptr, nullptr, nullptr, out);
}